// Round 1
// baseline (133.825 us; speedup 1.0000x reference)
//
#include <hip/hip_runtime.h>

// Problem dims (static, match reference)
#define N_PIX (512*512)   // pixels per sample
#define NFEAT 8
#define NCLUS 8
#define NB    4
#define WS_STRIDE 80      // per-sample floats in ws: [0..63] sums f*8+c, [64..71] counts, [72] dist_total

// ---------------------------------------------------------------------------
// Pass A: per-sample, per-cluster feature sums + pixel counts.
// 32-way replicated LDS accumulators (slot = lane&31) -> low-contention
// ds_add_f32; block partials folded via 72 global atomics into ws.
// ---------------------------------------------------------------------------
__global__ __launch_bounds__(256) void k_sums(const float* __restrict__ pred,
                                              const int* __restrict__ tgt,
                                              float* __restrict__ ws) {
    __shared__ float acc[72 * 32];
    const int tid = threadIdx.x;
    const int b = blockIdx.y;
    for (int i = tid; i < 72 * 32; i += 256) acc[i] = 0.0f;
    __syncthreads();

    const int slot = tid & 31;
    const int nChunks = N_PIX / 4;                 // float4/int4 chunks
    const int stride = gridDim.x * 256;
    const int4*  t4 = (const int4*)(tgt + b * N_PIX);
    const float4* p4 = (const float4*)(pred + (size_t)b * NFEAT * N_PIX);

    for (int i = blockIdx.x * 256 + tid; i < nChunks; i += stride) {
        int4 g4 = t4[i];
        float pr[NFEAT][4];
#pragma unroll
        for (int f = 0; f < NFEAT; ++f) {
            float4 v = p4[f * (N_PIX / 4) + i];
            pr[f][0] = v.x; pr[f][1] = v.y; pr[f][2] = v.z; pr[f][3] = v.w;
        }
        int gs[4] = {g4.x, g4.y, g4.z, g4.w};
#pragma unroll
        for (int j = 0; j < 4; ++j) {
            const int g = gs[j];
#pragma unroll
            for (int f = 0; f < NFEAT; ++f)
                atomicAdd(&acc[(f * 8 + g) * 32 + slot], pr[f][j]);
            atomicAdd(&acc[(64 + g) * 32 + slot], 1.0f);
        }
    }
    __syncthreads();

    for (int i = tid; i < 72; i += 256) {
        float s = 0.0f;
#pragma unroll
        for (int k = 0; k < 32; ++k) s += acc[i * 32 + k];
        unsafeAtomicAdd(&ws[b * WS_STRIDE + i], s);
    }
}

// ---------------------------------------------------------------------------
// Pass B: per-pixel Sum clip(||mu_g - p|| - 0.5, 0, 1e5)^2.
// Means in LDS with stride-9 padding: addr = c*9+f -> for fixed f the 8
// cluster addresses land in 8 distinct banks; same-address lanes broadcast.
// ---------------------------------------------------------------------------
__global__ __launch_bounds__(256) void k_var(const float* __restrict__ pred,
                                             const int* __restrict__ tgt,
                                             float* __restrict__ ws) {
    __shared__ float mean[NCLUS * 9];
    const int tid = threadIdx.x;
    const int b = blockIdx.y;
    if (tid < 64) {
        const int f = tid >> 3, c = tid & 7;
        mean[c * 9 + f] = ws[b * WS_STRIDE + tid] / ws[b * WS_STRIDE + 64 + c];
    }
    __syncthreads();

    const int nChunks = N_PIX / 4;
    const int stride = gridDim.x * 256;
    const int4*  t4 = (const int4*)(tgt + b * N_PIX);
    const float4* p4 = (const float4*)(pred + (size_t)b * NFEAT * N_PIX);

    float local = 0.0f;
    for (int i = blockIdx.x * 256 + tid; i < nChunks; i += stride) {
        int4 g4 = t4[i];
        float pr[NFEAT][4];
#pragma unroll
        for (int f = 0; f < NFEAT; ++f) {
            float4 v = p4[f * (N_PIX / 4) + i];
            pr[f][0] = v.x; pr[f][1] = v.y; pr[f][2] = v.z; pr[f][3] = v.w;
        }
        int gs[4] = {g4.x, g4.y, g4.z, g4.w};
#pragma unroll
        for (int j = 0; j < 4; ++j) {
            const float* m = &mean[gs[j] * 9];
            float dsq = 0.0f;
#pragma unroll
            for (int f = 0; f < NFEAT; ++f) {
                float d = m[f] - pr[f][j];
                dsq = fmaf(d, d, dsq);
            }
            float diff = sqrtf(dsq);
            float dm = fminf(fmaxf(diff - 0.5f, 0.0f), 100000.0f);
            local = fmaf(dm, dm, local);
        }
    }

    // wave (64-lane) shuffle reduction, then one global atomic per wave
#pragma unroll
    for (int o = 32; o >= 1; o >>= 1) local += __shfl_xor(local, o, 64);
    if ((tid & 63) == 0) unsafeAtomicAdd(&ws[b * WS_STRIDE + 72], local);
}

// ---------------------------------------------------------------------------
// Pass C: tiny epilogue. One block; wave b handles sample b.
// idx in [0,64): pair (i,j) = (idx>>3, idx&7) for l_dist; lanes with i==0
// additionally fold l_reg and the l_var "dist_total * Sum(1/count) / C" quirk.
// ---------------------------------------------------------------------------
__global__ __launch_bounds__(256) void k_final(const float* __restrict__ ws,
                                               float* __restrict__ out) {
    __shared__ float meanL[NB][64];
    __shared__ float sl[NB];
    const int tid = threadIdx.x;
    const int b = tid >> 6, idx = tid & 63;

    // idx enumerates exactly the 64 sums (f*8+c); count index = idx&7
    meanL[b][idx] = ws[b * WS_STRIDE + idx] / ws[b * WS_STRIDE + 64 + (idx & 7)];
    __syncthreads();

    const int i = idx >> 3, j = idx & 7;
    float pdsq = 0.0f;
#pragma unroll
    for (int f = 0; f < 8; ++f) {
        float d = meanL[b][f * 8 + i] - meanL[b][f * 8 + j];
        pdsq = fmaf(d, d, pdsq);
    }
    float nrm = sqrtf(pdsq);
    float t = fminf(fmaxf(3.0f - nrm, 0.0f), 100000.0f);  // margin = 2*delta_d
    float val = (i == j) ? 0.0f : t * t * (1.0f / 56.0f); // / (C*(C-1))

    if (i == 0) {  // 8 lanes: per-cluster l_reg + l_var quirk terms
        float rsq = 0.0f;
#pragma unroll
        for (int f = 0; f < 8; ++f) {
            float m = meanL[b][f * 8 + j];
            rsq = fmaf(m, m, rsq);
        }
        float r = sqrtf(rsq);
        float dist_total = ws[b * WS_STRIDE + 72];
        float invc = 1.0f / ws[b * WS_STRIDE + 64 + j];
        val += 0.001f * r * 0.125f + dist_total * invc * 0.125f;
    }

#pragma unroll
    for (int o = 32; o >= 1; o >>= 1) val += __shfl_xor(val, o, 64);
    if (idx == 0) sl[b] = val;
    __syncthreads();
    if (tid == 0) out[0] = (sl[0] + sl[1] + sl[2] + sl[3]) * 0.25f;
}

// ---------------------------------------------------------------------------
extern "C" void kernel_launch(void* const* d_in, const int* in_sizes, int n_in,
                              void* d_out, int out_size, void* d_ws, size_t ws_size,
                              hipStream_t stream) {
    const float* pred = (const float*)d_in[0];
    const int*   tgt  = (const int*)d_in[1];
    float* out = (float*)d_out;
    float* ws  = (float*)d_ws;

    // ws is re-poisoned to 0xAA before every timed launch -> zero what we use.
    hipMemsetAsync(d_ws, 0, NB * WS_STRIDE * sizeof(float), stream);

    dim3 grid(128, NB);   // 512 blocks total, 2 per CU
    k_sums<<<grid, 256, 0, stream>>>(pred, tgt, ws);
    k_var <<<grid, 256, 0, stream>>>(pred, tgt, ws);
    k_final<<<1, 256, 0, stream>>>(ws, out);
}

// Round 2
// 91.836 us; speedup vs baseline: 1.4572x; 1.4572x over previous
//
#include <hip/hip_runtime.h>

// Problem dims (static, match reference)
#define N_PIX (512*512)
#define NFEAT 8
#define NCLUS 8
#define NB    4
#define GRIDX 128                 // blocks per sample; 512 blocks total = 2/CU
#define NCHUNK (N_PIX/4)          // 65536 float4/int4 chunks per sample
#define STRIDE (GRIDX*256)        // 32768 -> compile-time 2 iterations/thread
#define PART_STRIDE 80            // per-(replica,sample) floats: [0..63] sums f*8+c, [64..71] counts
#define DIST_OFF (GRIDX*NB*PART_STRIDE)   // 40960 floats
#define NREP_D 16                 // dist-accumulator replicas (atomic chain = GRIDX/NREP_D = 8)
#define S2_OFF (DIST_OFF + NREP_D*NB)     // staged per-sample totals for k_final

// ---------------------------------------------------------------------------
// Pass A: per-sample per-cluster feature sums + counts.
// Register select-FMA accumulation (NO atomics), ballot-based counts (scalar
// pipe), 6-round reduce-scatter butterfly (lane L ends with wave total of
// entry L), block fold via tiny LDS, plain stores of per-block partials.
// ---------------------------------------------------------------------------
__global__ __launch_bounds__(256) void k_sums(const float* __restrict__ pred,
                                              const int* __restrict__ tgt,
                                              float* __restrict__ ws) {
    const int tid = threadIdx.x;
    const int bx = blockIdx.x, b = blockIdx.y;
    const int lane = tid & 63, w = tid >> 6;

    float acc[64];
#pragma unroll
    for (int i = 0; i < 64; ++i) acc[i] = 0.0f;
    int cnt[8] = {0, 0, 0, 0, 0, 0, 0, 0};

    const int4*   t4 = (const int4*)(tgt + b * N_PIX);
    const float4* p4 = (const float4*)(pred + (size_t)b * NFEAT * N_PIX);

#pragma unroll
    for (int it = 0; it < NCHUNK / STRIDE; ++it) {
        const int i = bx * 256 + tid + it * STRIDE;
        int4 g4 = t4[i];
        int gs[4] = {g4.x, g4.y, g4.z, g4.w};
        float pr[NFEAT][4];
#pragma unroll
        for (int f = 0; f < NFEAT; ++f) {
            float4 v = p4[f * NCHUNK + i];
            pr[f][0] = v.x; pr[f][1] = v.y; pr[f][2] = v.z; pr[f][3] = v.w;
        }
#pragma unroll
        for (int j = 0; j < 4; ++j) {
            float m[NCLUS];
#pragma unroll
            for (int c = 0; c < NCLUS; ++c) {
                bool hit = (gs[j] == c);
                m[c] = hit ? 1.0f : 0.0f;
                cnt[c] += (int)__popcll(__ballot(hit));   // wave-uniform, scalar adds
            }
#pragma unroll
            for (int f = 0; f < NFEAT; ++f)
#pragma unroll
                for (int c = 0; c < NCLUS; ++c)
                    acc[f * 8 + c] = fmaf(m[c], pr[f][j], acc[f * 8 + c]);
        }
    }

    // Reduce-scatter butterfly over the 64-lane wave: after round k, acc[p]
    // holds the partial of entry (p<<(k+1)) | (lane & ((2<<k)-1)) summed over
    // the lane's 2^(k+1)-group. After 6 rounds: acc[0] = wave total of entry
    // 'lane'. ~315 VALU ops total vs 864 for the naive 72x6 butterfly.
#pragma unroll
    for (int k = 0; k < 6; ++k) {
        const int d = 1 << k;
        const int bit = (lane >> k) & 1;
#pragma unroll
        for (int p = 0; p < (64 >> 1); ++p) {
            if (p >= (64 >> (k + 1))) break;
            float a  = __shfl_xor(acc[2 * p],     d, 64);
            float bb = __shfl_xor(acc[2 * p + 1], d, 64);
            float own = bit ? acc[2 * p + 1] : acc[2 * p];
            float oth = bit ? bb : a;
            acc[p] = own + oth;      // safe: writes index p after reading 2p,2p+1
        }
    }

    __shared__ float ssum[4][64];
    __shared__ float scnt[4][8];
    ssum[w][lane] = acc[0];
    if (lane == 0) {
#pragma unroll
        for (int c = 0; c < NCLUS; ++c) scnt[w][c] = (float)cnt[c];
    }
    __syncthreads();

    if (tid < 72) {
        float s;
        if (tid < 64) s = ssum[0][tid] + ssum[1][tid] + ssum[2][tid] + ssum[3][tid];
        else { int c = tid - 64; s = scnt[0][c] + scnt[1][c] + scnt[2][c] + scnt[3][c]; }
        ws[(bx * NB + b) * PART_STRIDE + tid] = s;   // plain store, no atomic
    }
    // zero the dist replica slots (k_var runs strictly after us on the stream)
    if (tid == 0 && bx < NREP_D) ws[DIST_OFF + bx * NB + b] = 0.0f;
}

// ---------------------------------------------------------------------------
// Pass B: Sum clip(||mu_g - p|| - 0.5, 0, 1e5)^2 over pixels.
// Prologue folds the GRIDX block-partials into means (LDS, stride-9 padded:
// banks 9g+f mod 32 distinct over g -> conflict-free; same-g lanes broadcast).
// Epilogue: ONE atomic per block into 16 replicas (chain = 8, was 512).
// ---------------------------------------------------------------------------
__global__ __launch_bounds__(256) void k_var(const float* __restrict__ pred,
                                             const int* __restrict__ tgt,
                                             float* __restrict__ ws) {
    __shared__ float raw[72];
    __shared__ float mean[NCLUS * 9];
    __shared__ float sl[4];
    const int tid = threadIdx.x;
    const int bx = blockIdx.x, b = blockIdx.y;

    if (tid < 72) {
        float s = 0.0f;
        for (int r = 0; r < GRIDX; ++r)
            s += ws[(r * NB + b) * PART_STRIDE + tid];
        raw[tid] = s;
        if (bx == 0) ws[S2_OFF + b * PART_STRIDE + tid] = s;  // stage for k_final
    }
    __syncthreads();
    if (tid < 64) {
        const int f = tid >> 3, c = tid & 7;
        mean[c * 9 + f] = raw[f * 8 + c] / raw[64 + c];
    }
    __syncthreads();

    const int4*   t4 = (const int4*)(tgt + b * N_PIX);
    const float4* p4 = (const float4*)(pred + (size_t)b * NFEAT * N_PIX);

    float local = 0.0f;
#pragma unroll
    for (int it = 0; it < NCHUNK / STRIDE; ++it) {
        const int i = bx * 256 + tid + it * STRIDE;
        int4 g4 = t4[i];
        int gs[4] = {g4.x, g4.y, g4.z, g4.w};
        float pr[NFEAT][4];
#pragma unroll
        for (int f = 0; f < NFEAT; ++f) {
            float4 v = p4[f * NCHUNK + i];
            pr[f][0] = v.x; pr[f][1] = v.y; pr[f][2] = v.z; pr[f][3] = v.w;
        }
#pragma unroll
        for (int j = 0; j < 4; ++j) {
            const float* m = &mean[gs[j] * 9];
            float dsq = 0.0f;
#pragma unroll
            for (int f = 0; f < NFEAT; ++f) {
                float d = m[f] - pr[f][j];
                dsq = fmaf(d, d, dsq);
            }
            float diff = sqrtf(dsq);
            float dm = fminf(fmaxf(diff - 0.5f, 0.0f), 100000.0f);
            local = fmaf(dm, dm, local);
        }
    }

#pragma unroll
    for (int o = 32; o >= 1; o >>= 1) local += __shfl_xor(local, o, 64);
    if ((tid & 63) == 0) sl[tid >> 6] = local;
    __syncthreads();
    if (tid == 0)
        unsafeAtomicAdd(&ws[DIST_OFF + (bx & (NREP_D - 1)) * NB + b],
                        sl[0] + sl[1] + sl[2] + sl[3]);
}

// ---------------------------------------------------------------------------
// Pass C: tiny epilogue, one block. Wave b handles sample b; pair (i,j) for
// l_dist; i==0 lanes fold l_reg and the l_var "dist_total * Sum(1/count) / C"
// quirk. Math identical to the round-1 version that validated absmax 0.0.
// ---------------------------------------------------------------------------
__global__ __launch_bounds__(256) void k_final(const float* __restrict__ ws,
                                               float* __restrict__ out) {
    __shared__ float meanL[NB][64];
    __shared__ float sl[NB];
    const int tid = threadIdx.x;
    const int b = tid >> 6, idx = tid & 63;
    const float* S2 = ws + S2_OFF + b * PART_STRIDE;

    meanL[b][idx] = S2[idx] / S2[64 + (idx & 7)];
    __syncthreads();

    const int i = idx >> 3, j = idx & 7;
    float pdsq = 0.0f;
#pragma unroll
    for (int f = 0; f < 8; ++f) {
        float d = meanL[b][f * 8 + i] - meanL[b][f * 8 + j];
        pdsq = fmaf(d, d, pdsq);
    }
    float nrm = sqrtf(pdsq);
    float t = fminf(fmaxf(3.0f - nrm, 0.0f), 100000.0f);   // margin = 2*delta_d
    float val = (i == j) ? 0.0f : t * t * (1.0f / 56.0f);  // / (C*(C-1))

    if (i == 0) {
        float rsq = 0.0f;
#pragma unroll
        for (int f = 0; f < 8; ++f) {
            float m = meanL[b][f * 8 + j];
            rsq = fmaf(m, m, rsq);
        }
        float dist_total = 0.0f;
#pragma unroll
        for (int r = 0; r < NREP_D; ++r) dist_total += ws[DIST_OFF + r * NB + b];
        float invc = 1.0f / S2[64 + j];
        val += 0.001f * sqrtf(rsq) * 0.125f + dist_total * invc * 0.125f;
    }

#pragma unroll
    for (int o = 32; o >= 1; o >>= 1) val += __shfl_xor(val, o, 64);
    if (idx == 0) sl[b] = val;
    __syncthreads();
    if (tid == 0) out[0] = (sl[0] + sl[1] + sl[2] + sl[3]) * 0.25f;
}

// ---------------------------------------------------------------------------
extern "C" void kernel_launch(void* const* d_in, const int* in_sizes, int n_in,
                              void* d_out, int out_size, void* d_ws, size_t ws_size,
                              hipStream_t stream) {
    const float* pred = (const float*)d_in[0];
    const int*   tgt  = (const int*)d_in[1];
    float* out = (float*)d_out;
    float* ws  = (float*)d_ws;

    dim3 grid(GRIDX, NB);   // 512 blocks, 2/CU
    k_sums<<<grid, 256, 0, stream>>>(pred, tgt, ws);   // zeroes dist slots itself
    k_var <<<grid, 256, 0, stream>>>(pred, tgt, ws);
    k_final<<<1, 256, 0, stream>>>(ws, out);
}